// Round 1
// baseline (478.226 us; speedup 1.0000x reference)
//
#include <hip/hip_runtime.h>

#define B_ 2
#define S_ 2048
#define L_ 2048
#define H_ 16
#define KVH_ 4
#define D_ 128
#define HID_ 2048
#define EPS_ 1e-6f

typedef unsigned short u16;
typedef unsigned int u32;
typedef __bf16 bf16x8 __attribute__((ext_vector_type(8)));
typedef float f32x4 __attribute__((ext_vector_type(4)));

__device__ __forceinline__ float bf2f(u16 u) {
  union { u32 i; float f; } x; x.i = ((u32)u) << 16; return x.f;
}
__device__ __forceinline__ u16 f2bf(float f) {
  union { float f; u32 i; } x; x.f = f;
  return (u16)((x.i + 0x7fffu + ((x.i >> 16) & 1u)) >> 16);
}
// async global->LDS, 16B per lane. LDS dest = wave-uniform base + lane*16.
__device__ __forceinline__ void gl2lds16(const u16* g, u16* l) {
  __builtin_amdgcn_global_load_lds(
      (const __attribute__((address_space(1))) u32*)g,
      (__attribute__((address_space(3))) u32*)l, 16, 0, 0);
}

// ---------------- elementwise fp32 -> bf16 cast ----------------
__global__ __launch_bounds__(256) void cvt_bf16(const float* __restrict__ in,
                                                u16* __restrict__ out, int n4) {
  int i = blockIdx.x * 256 + threadIdx.x;
  if (i >= n4) return;
  float4 v = ((const float4*)in)[i];
  u32 lo = (u32)f2bf(v.x) | ((u32)f2bf(v.y) << 16);
  u32 hi = (u32)f2bf(v.z) | ((u32)f2bf(v.w) << 16);
  uint2 o; o.x = lo; o.y = hi;
  ((uint2*)out)[i] = o;
}

// ---------------- LDS-tiled transpose fp32[R][C] -> bf16[C][R] ----------------
__global__ __launch_bounds__(256) void transp_bf16(const float* __restrict__ A,
                                                   u16* __restrict__ At, int R, int C) {
  __shared__ float t[64][65];
  int c0 = blockIdx.x * 64, r0 = blockIdx.y * 64;
  int tx = threadIdx.x & 63, ty = threadIdx.x >> 6;
  for (int i = ty; i < 64; i += 4)
    t[i][tx] = A[(size_t)(r0 + i) * C + c0 + tx];
  __syncthreads();
  for (int i = ty; i < 64; i += 4)
    At[(size_t)(c0 + i) * R + r0 + tx] = f2bf(t[tx][i]);
}

// ---------------- bf16 GEMM: C[M][N] = A[M][K] @ Bt[N][K]^T ----------------
// m97 structure: 128x128 tile, BK=32, 4 waves (2x2 of 64x64), 16x16x32 MFMA.
__device__ __forceinline__ void store_out(u16* p, float v) { *p = f2bf(v); }
__device__ __forceinline__ void store_out(float* p, float v) { *p = v; }

template <typename OutT>
__global__ __launch_bounds__(256, 2) void gemm_bt(const u16* __restrict__ A,
                                                  const u16* __restrict__ Bt,
                                                  OutT* __restrict__ C,
                                                  int M, int N, int K) {
  __shared__ u16 sA[128 * 32];
  __shared__ u16 sB[128 * 32];
  const int tid = threadIdx.x;
  const int wave = tid >> 6, lane = tid & 63;
  const int quad = lane >> 4, l15 = lane & 15;
  const int m0 = blockIdx.x * 128, n0 = blockIdx.y * 128;
  const int wm = (wave >> 1) * 64, wn = (wave & 1) * 64;
  const u16* aP = A + (size_t)m0 * K;
  const u16* bP = Bt + (size_t)n0 * K;
  const int sr = lane >> 2;           // staging row within 16-row chunk
  const int sc = (lane & 3) * 8;      // staging col (8 bf16 = 16B)
  const int r0 = wave * 32, r1 = wave * 32 + 16;

  f32x4 acc[4][4];
  for (int i = 0; i < 4; i++)
    for (int j = 0; j < 4; j++)
      for (int r = 0; r < 4; r++) acc[i][j][r] = 0.0f;

  for (int k0 = 0; k0 < K; k0 += 32) {
    gl2lds16(aP + (size_t)(r0 + sr) * K + k0 + sc, &sA[r0 * 32]);
    gl2lds16(aP + (size_t)(r1 + sr) * K + k0 + sc, &sA[r1 * 32]);
    gl2lds16(bP + (size_t)(r0 + sr) * K + k0 + sc, &sB[r0 * 32]);
    gl2lds16(bP + (size_t)(r1 + sr) * K + k0 + sc, &sB[r1 * 32]);
    __syncthreads();  // drains vmcnt -> LDS tiles ready
    bf16x8 afrag[4], bfrag[4];
    for (int i = 0; i < 4; i++)
      afrag[i] = *(const bf16x8*)&sA[(wm + i * 16 + l15) * 32 + quad * 8];
    for (int j = 0; j < 4; j++)
      bfrag[j] = *(const bf16x8*)&sB[(wn + j * 16 + l15) * 32 + quad * 8];
    for (int i = 0; i < 4; i++)
      for (int j = 0; j < 4; j++)
        acc[i][j] = __builtin_amdgcn_mfma_f32_16x16x32_bf16(afrag[i], bfrag[j], acc[i][j], 0, 0, 0);
    __syncthreads();  // before next-iter staging overwrites LDS
  }
  // epilogue: C/D layout col=lane&15, row=quad*4+reg (m89-verified)
  for (int i = 0; i < 4; i++)
    for (int j = 0; j < 4; j++) {
      int row = m0 + wm + i * 16 + quad * 4;
      int col = n0 + wn + j * 16 + l15;
      for (int r = 0; r < 4; r++)
        store_out(&C[(size_t)(row + r) * N + col], acc[i][j][r]);
    }
}

// ---------------- per-head RMSNorm on Q, in place (bf16) ----------------
// XQ is [B*S][HID]; head-rows of 128 are contiguous. One wave per head-row.
__global__ __launch_bounds__(256) void rmsnorm_q(u16* __restrict__ XQ,
                                                 const float* __restrict__ w) {
  int gw = blockIdx.x * 4 + (threadIdx.x >> 6);
  int lane = threadIdx.x & 63;
  u16* base = XQ + (size_t)gw * 128;
  float x0 = bf2f(base[lane]), x1 = bf2f(base[lane + 64]);
  float ss = x0 * x0 + x1 * x1;
  for (int off = 1; off < 64; off <<= 1) ss += __shfl_xor(ss, off);
  float scale = rsqrtf(ss * (1.0f / 128.0f) + EPS_);
  base[lane] = f2bf(x0 * scale * w[lane]);
  base[lane + 64] = f2bf(x1 * scale * w[lane + 64]);
}

// ---------------- K-norm + deinterleave CKV -> K, V^T ----------------
// CKV [B*L][KVH*D*2], cols = kvh*256 + d*2 + {0=k,1=v}
// K   [B][KVH][L][D]   (RMSNormed, bf16)
// Vt  [B][KVH][D][L]   (bf16)
__global__ __launch_bounds__(256) void knorm_deint(const u16* __restrict__ CKV,
                                                   const float* __restrict__ w,
                                                   u16* __restrict__ K,
                                                   u16* __restrict__ Vt) {
  int gw = blockIdx.x * 4 + (threadIdx.x >> 6);  // over (b*L+l)*KVH + kvh
  int lane = threadIdx.x & 63;
  int kvh = gw & 3;
  int row = gw >> 2;            // b*L + l
  int b = row >> 11, l = row & 2047;
  const u16* src = CKV + (size_t)row * 1024 + kvh * 256;
  u32 p0 = *(const u32*)&src[lane * 2];         // (k,v) for d=lane
  u32 p1 = *(const u32*)&src[(lane + 64) * 2];  // (k,v) for d=lane+64
  float k0 = bf2f((u16)(p0 & 0xffff)), v0 = bf2f((u16)(p0 >> 16));
  float k1 = bf2f((u16)(p1 & 0xffff)), v1 = bf2f((u16)(p1 >> 16));
  float ss = k0 * k0 + k1 * k1;
  for (int off = 1; off < 64; off <<= 1) ss += __shfl_xor(ss, off);
  float scale = rsqrtf(ss * (1.0f / 128.0f) + EPS_);
  size_t kb = (((size_t)b * KVH_ + kvh) * L_ + l) * D_;
  K[kb + lane] = f2bf(k0 * scale * w[lane]);
  K[kb + lane + 64] = f2bf(k1 * scale * w[lane + 64]);
  size_t vb = (((size_t)b * KVH_ + kvh) * D_) * L_ + l;
  Vt[vb + (size_t)lane * L_] = f2bf(v0);
  Vt[vb + (size_t)(lane + 64) * L_] = f2bf(v1);
}

// ---------------- flash attention ----------------
// grid (S/128, H, B), 256 threads. Q-tile 128 rows; KV tiles of 64.
// Each wave owns 32 q-rows: 2 qsubs x (4 lsubs | 8 dsubs) of 16x16 frags.
__global__ __launch_bounds__(256, 2) void attn(const u16* __restrict__ Q,
                                               const u16* __restrict__ K,
                                               const u16* __restrict__ Vt,
                                               u16* __restrict__ AO) {
  __shared__ union {
    u16 q[128 * 136];                         // padded stride: 2-way-free bank pattern
    struct {
      u16 k[4][64 * 32];                      // [kchunk d/32][l][32]  (global_load_lds: no pad)
      u16 v[2][128 * 32];                     // [lchunk l/32][d][32]
      u16 p[4][32 * 72];                      // per-wave P scratch, padded
    } s;
  } sm;
  const int tid = threadIdx.x, wave = tid >> 6, lane = tid & 63;
  const int quad = lane >> 4, l15 = lane & 15;
  const int qt = blockIdx.x, h = blockIdx.y, b = blockIdx.z;
  const int kvh = h >> 2;
  const int s0 = qt * 128;
  const float cexp = 0.12753102331322172f;    // (1/sqrt(128)) * log2(e)

  // Q tile -> LDS (vectorized), then per-wave A-frags to registers
  const u16* qbase = Q + (size_t)(b * S_ + s0) * HID_ + h * D_;
  for (int it = tid; it < 128 * 16; it += 256) {
    int r = it >> 4, c = (it & 15) * 8;
    *(uint4*)&sm.q[r * 136 + c] = *(const uint4*)&qbase[(size_t)r * HID_ + c];
  }
  __syncthreads();
  const int wr0 = wave * 32;
  bf16x8 qf[2][4];
  for (int i = 0; i < 2; i++)
    for (int kc = 0; kc < 4; kc++)
      qf[i][kc] = *(const bf16x8*)&sm.q[(wr0 + i * 16 + l15) * 136 + kc * 32 + quad * 8];
  __syncthreads();  // Q region now reusable

  float mrow[2][4], lrow[2][4];
  f32x4 o[2][8];
  for (int i = 0; i < 2; i++)
    for (int r = 0; r < 4; r++) { mrow[i][r] = -1e30f; lrow[i][r] = 0.0f; }
  for (int i = 0; i < 2; i++)
    for (int n = 0; n < 8; n++)
      for (int r = 0; r < 4; r++) o[i][n][r] = 0.0f;

  const u16* kbase = K + ((size_t)(b * KVH_ + kvh) * L_) * D_;
  const u16* vbase = Vt + ((size_t)(b * KVH_ + kvh) * D_) * L_;

  for (int l0 = 0; l0 < L_; l0 += 64) {
    // stage K tile: wave w stages k-chunk c=w ([64 l][32 d])
    {
      const u16* kb = kbase + (size_t)l0 * D_ + wave * 32;
      for (int is = 0; is < 4; is++)
        gl2lds16(kb + (size_t)(is * 16 + (lane >> 2)) * D_ + (lane & 3) * 8,
                 &sm.s.k[wave][is * 16 * 32]);
      // stage Vt tile: chunk c=wave>>1, rows (wave&1)*64 + j*16
      const int c = wave >> 1;
      const u16* vb = vbase + l0 + c * 32;
      for (int j = 0; j < 4; j++) {
        int dr = (wave & 1) * 64 + j * 16;
        gl2lds16(vb + (size_t)(dr + (lane >> 2)) * L_ + (lane & 3) * 8,
                 &sm.s.v[c][dr * 32]);
      }
    }
    __syncthreads();

    // S = Q K^T (raw scores; SCALE folded into exp2 constant)
    f32x4 sacc[2][4];
    for (int i = 0; i < 2; i++)
      for (int j = 0; j < 4; j++)
        for (int r = 0; r < 4; r++) sacc[i][j][r] = 0.0f;
    for (int j = 0; j < 4; j++) {
      bf16x8 kf[4];
      for (int kc = 0; kc < 4; kc++)
        kf[kc] = *(const bf16x8*)&sm.s.k[kc][(j * 16 + l15) * 32 + quad * 8];
      for (int i = 0; i < 2; i++)
        for (int kc = 0; kc < 4; kc++)
          sacc[i][j] = __builtin_amdgcn_mfma_f32_16x16x32_bf16(qf[i][kc], kf[kc], sacc[i][j], 0, 0, 0);
    }

    // online softmax (fp32), P -> per-wave LDS (bf16)
    for (int i = 0; i < 2; i++) {
      float alpha[4];
      for (int r = 0; r < 4; r++) {
        float mx = fmaxf(fmaxf(sacc[i][0][r], sacc[i][1][r]),
                         fmaxf(sacc[i][2][r], sacc[i][3][r]));
        for (int off = 1; off < 16; off <<= 1) mx = fmaxf(mx, __shfl_xor(mx, off));
        float mnew = fmaxf(mrow[i][r], mx);
        alpha[r] = exp2f((mrow[i][r] - mnew) * cexp);
        mrow[i][r] = mnew;
        float rs = 0.0f;
        for (int j = 0; j < 4; j++) {
          float p = exp2f((sacc[i][j][r] - mnew) * cexp);
          sacc[i][j][r] = p;
          rs += p;
        }
        for (int off = 1; off < 16; off <<= 1) rs += __shfl_xor(rs, off);
        lrow[i][r] = lrow[i][r] * alpha[r] + rs;
      }
      for (int n = 0; n < 8; n++)
        for (int r = 0; r < 4; r++) o[i][n][r] *= alpha[r];
      for (int j = 0; j < 4; j++)
        for (int r = 0; r < 4; r++)
          sm.s.p[wave][(i * 16 + quad * 4 + r) * 72 + j * 16 + l15] = f2bf(sacc[i][j][r]);
    }

    // O += P V  (P via LDS round-trip into A-layout)
    for (int kc2 = 0; kc2 < 2; kc2++) {
      bf16x8 pf[2];
      for (int i = 0; i < 2; i++)
        pf[i] = *(const bf16x8*)&sm.s.p[wave][(i * 16 + l15) * 72 + kc2 * 32 + quad * 8];
      for (int n = 0; n < 8; n++) {
        bf16x8 vf = *(const bf16x8*)&sm.s.v[kc2][(n * 16 + l15) * 32 + quad * 8];
        for (int i = 0; i < 2; i++)
          o[i][n] = __builtin_amdgcn_mfma_f32_16x16x32_bf16(pf[i], vf, o[i][n], 0, 0, 0);
      }
    }
    __syncthreads();
  }

  // epilogue: O / l -> AO bf16
  u16* obase = AO + (size_t)(b * S_ + s0 + wr0) * HID_ + h * D_;
  for (int i = 0; i < 2; i++)
    for (int n = 0; n < 8; n++)
      for (int r = 0; r < 4; r++) {
        float val = o[i][n][r] / lrow[i][r];
        obase[(size_t)(i * 16 + quad * 4 + r) * HID_ + n * 16 + l15] = f2bf(val);
      }
}

// ---------------- launch ----------------
extern "C" void kernel_launch(void* const* d_in, const int* in_sizes, int n_in,
                              void* d_out, int out_size, void* d_ws, size_t ws_size,
                              hipStream_t stream) {
  const float* x = (const float*)d_in[0];
  const float* c = (const float*)d_in[1];
  const float* wq = (const float*)d_in[2];
  const float* wkv = (const float*)d_in[3];
  const float* wo = (const float*)d_in[4];
  const float* nqw = (const float*)d_in[5];
  const float* nkw = (const float*)d_in[6];
  float* out = (float*)d_out;

  const int M = B_ * S_;  // 4096
  char* p = (char*)d_ws;
  auto alloc = [&](size_t bytes) {
    char* r = p;
    p += (bytes + 255) & ~(size_t)255;
    return r;
  };
  u16* xbf = (u16*)alloc((size_t)M * HID_ * 2);          // 16 MB
  u16* cbf = (u16*)alloc((size_t)M * HID_ * 2);          // 16 MB
  u16* wqT = (u16*)alloc((size_t)HID_ * HID_ * 2);       // 8 MB
  u16* wkvT = (u16*)alloc((size_t)1024 * HID_ * 2);      // 4 MB
  u16* woT = (u16*)alloc((size_t)HID_ * HID_ * 2);       // 8 MB
  u16* XQ = (u16*)alloc((size_t)M * HID_ * 2);           // 16 MB
  u16* CKV = (u16*)alloc((size_t)M * 1024 * 2);          // 8 MB
  u16* Kb = (u16*)alloc((size_t)B_ * KVH_ * L_ * D_ * 2);   // 4 MB
  u16* Vt = (u16*)alloc((size_t)B_ * KVH_ * D_ * L_ * 2);   // 4 MB
  u16* AO = (u16*)alloc((size_t)M * HID_ * 2);           // 16 MB

  cvt_bf16<<<8192, 256, 0, stream>>>(x, xbf, M * HID_ / 4);
  cvt_bf16<<<8192, 256, 0, stream>>>(c, cbf, M * HID_ / 4);
  transp_bf16<<<dim3(32, 32), 256, 0, stream>>>(wq, wqT, HID_, HID_);
  transp_bf16<<<dim3(16, 32), 256, 0, stream>>>(wkv, wkvT, HID_, 1024);
  transp_bf16<<<dim3(32, 32), 256, 0, stream>>>(wo, woT, HID_, HID_);
  gemm_bt<u16><<<dim3(32, 16), 256, 0, stream>>>(xbf, wqT, XQ, M, HID_, HID_);
  gemm_bt<u16><<<dim3(32, 8), 256, 0, stream>>>(cbf, wkvT, CKV, M, 1024, HID_);
  rmsnorm_q<<<16384, 256, 0, stream>>>(XQ, nqw);
  knorm_deint<<<4096, 256, 0, stream>>>(CKV, nkw, Kb, Vt);
  attn<<<dim3(16, 16, 2), 256, 0, stream>>>(XQ, Kb, Vt, AO);
  gemm_bt<float><<<dim3(32, 16), 256, 0, stream>>>(AO, woT, out, M, HID_, HID_);
}

// Round 2
// 422.674 us; speedup vs baseline: 1.1314x; 1.1314x over previous
//
#include <hip/hip_runtime.h>

#define B_ 2
#define S_ 2048
#define L_ 2048
#define H_ 16
#define KVH_ 4
#define D_ 128
#define HID_ 2048
#define EPS_ 1e-6f

typedef unsigned short u16;
typedef unsigned int u32;
typedef __bf16 bf16x8 __attribute__((ext_vector_type(8)));
typedef float f32x4 __attribute__((ext_vector_type(4)));

__device__ __forceinline__ float bf2f(u16 u) {
  union { u32 i; float f; } x; x.i = ((u32)u) << 16; return x.f;
}
__device__ __forceinline__ u16 f2bf(float f) {
  union { float f; u32 i; } x; x.f = f;
  return (u16)((x.i + 0x7fffu + ((x.i >> 16) & 1u)) >> 16);
}
// async global->LDS, 16B per lane. LDS dest = wave-uniform base + lane*16.
__device__ __forceinline__ void gl2lds16(const u16* g, u16* l) {
  __builtin_amdgcn_global_load_lds(
      (const __attribute__((address_space(1))) u32*)g,
      (__attribute__((address_space(3))) u32*)l, 16, 0, 0);
}

// ---------------- elementwise fp32 -> bf16 cast ----------------
__global__ __launch_bounds__(256) void cvt_bf16(const float* __restrict__ in,
                                                u16* __restrict__ out, int n4) {
  int i = blockIdx.x * 256 + threadIdx.x;
  if (i >= n4) return;
  float4 v = ((const float4*)in)[i];
  u32 lo = (u32)f2bf(v.x) | ((u32)f2bf(v.y) << 16);
  u32 hi = (u32)f2bf(v.z) | ((u32)f2bf(v.w) << 16);
  uint2 o; o.x = lo; o.y = hi;
  ((uint2*)out)[i] = o;
}

// ---------------- LDS-tiled transpose fp32[R][C] -> bf16[C][R] ----------------
__global__ __launch_bounds__(256) void transp_bf16(const float* __restrict__ A,
                                                   u16* __restrict__ At, int R, int C) {
  __shared__ float t[64][65];
  int c0 = blockIdx.x * 64, r0 = blockIdx.y * 64;
  int tx = threadIdx.x & 63, ty = threadIdx.x >> 6;
  for (int i = ty; i < 64; i += 4)
    t[i][tx] = A[(size_t)(r0 + i) * C + c0 + tx];
  __syncthreads();
  for (int i = ty; i < 64; i += 4)
    At[(size_t)(c0 + i) * R + r0 + tx] = f2bf(t[tx][i]);
}

// ---------------- bf16 GEMM: C[M][N] = A[M][K] @ Bt[N][K]^T ----------------
// m97 structure: 128x128 tile, BK=32, 4 waves (2x2 of 64x64), 16x16x32 MFMA.
__device__ __forceinline__ void store_out(u16* p, float v) { *p = f2bf(v); }
__device__ __forceinline__ void store_out(float* p, float v) { *p = v; }

template <typename OutT>
__global__ __launch_bounds__(256, 2) void gemm_bt(const u16* __restrict__ A,
                                                  const u16* __restrict__ Bt,
                                                  OutT* __restrict__ C,
                                                  int M, int N, int K) {
  __shared__ u16 sA[128 * 32];
  __shared__ u16 sB[128 * 32];
  const int tid = threadIdx.x;
  const int wave = tid >> 6, lane = tid & 63;
  const int quad = lane >> 4, l15 = lane & 15;
  const int m0 = blockIdx.x * 128, n0 = blockIdx.y * 128;
  const int wm = (wave >> 1) * 64, wn = (wave & 1) * 64;
  const u16* aP = A + (size_t)m0 * K;
  const u16* bP = Bt + (size_t)n0 * K;
  const int sr = lane >> 2;           // staging row within 16-row chunk
  const int sc = (lane & 3) * 8;      // staging col (8 bf16 = 16B)
  const int r0 = wave * 32, r1 = wave * 32 + 16;

  f32x4 acc[4][4];
  for (int i = 0; i < 4; i++)
    for (int j = 0; j < 4; j++)
      for (int r = 0; r < 4; r++) acc[i][j][r] = 0.0f;

  for (int k0 = 0; k0 < K; k0 += 32) {
    gl2lds16(aP + (size_t)(r0 + sr) * K + k0 + sc, &sA[r0 * 32]);
    gl2lds16(aP + (size_t)(r1 + sr) * K + k0 + sc, &sA[r1 * 32]);
    gl2lds16(bP + (size_t)(r0 + sr) * K + k0 + sc, &sB[r0 * 32]);
    gl2lds16(bP + (size_t)(r1 + sr) * K + k0 + sc, &sB[r1 * 32]);
    __syncthreads();  // drains vmcnt -> LDS tiles ready
    bf16x8 afrag[4], bfrag[4];
    for (int i = 0; i < 4; i++)
      afrag[i] = *(const bf16x8*)&sA[(wm + i * 16 + l15) * 32 + quad * 8];
    for (int j = 0; j < 4; j++)
      bfrag[j] = *(const bf16x8*)&sB[(wn + j * 16 + l15) * 32 + quad * 8];
    for (int i = 0; i < 4; i++)
      for (int j = 0; j < 4; j++)
        acc[i][j] = __builtin_amdgcn_mfma_f32_16x16x32_bf16(afrag[i], bfrag[j], acc[i][j], 0, 0, 0);
    __syncthreads();  // before next-iter staging overwrites LDS
  }
  // epilogue: C/D layout col=lane&15, row=quad*4+reg (m89-verified)
  for (int i = 0; i < 4; i++)
    for (int j = 0; j < 4; j++) {
      int row = m0 + wm + i * 16 + quad * 4;
      int col = n0 + wn + j * 16 + l15;
      for (int r = 0; r < 4; r++)
        store_out(&C[(size_t)(row + r) * N + col], acc[i][j][r]);
    }
}

// ---------------- per-head RMSNorm on Q, in place (bf16) ----------------
// XQ is [B*S][HID]; head-rows of 128 are contiguous. One wave per head-row.
// Also folds the attention scale SCALE*log2(e) so attn can use exp2 directly.
__global__ __launch_bounds__(256) void rmsnorm_q(u16* __restrict__ XQ,
                                                 const float* __restrict__ w) {
  int gw = blockIdx.x * 4 + (threadIdx.x >> 6);
  int lane = threadIdx.x & 63;
  u16* base = XQ + (size_t)gw * 128;
  float x0 = bf2f(base[lane]), x1 = bf2f(base[lane + 64]);
  float ss = x0 * x0 + x1 * x1;
  for (int off = 1; off < 64; off <<= 1) ss += __shfl_xor(ss, off);
  const float cexp = 0.12753102331322172f;  // (1/sqrt(128)) * log2(e)
  float scale = rsqrtf(ss * (1.0f / 128.0f) + EPS_) * cexp;
  base[lane] = f2bf(x0 * scale * w[lane]);
  base[lane + 64] = f2bf(x1 * scale * w[lane + 64]);
}

// ---------------- K-norm + deinterleave CKV -> K, V^T ----------------
// CKV [B*L][KVH*D*2], cols = kvh*256 + d*2 + {0=k,1=v}
// K   [B][KVH][L][D]   (RMSNormed, bf16)
// Vt  [B][KVH][D][L]   (bf16)
__global__ __launch_bounds__(256) void knorm_deint(const u16* __restrict__ CKV,
                                                   const float* __restrict__ w,
                                                   u16* __restrict__ K,
                                                   u16* __restrict__ Vt) {
  int gw = blockIdx.x * 4 + (threadIdx.x >> 6);  // over (b*L+l)*KVH + kvh
  int lane = threadIdx.x & 63;
  int kvh = gw & 3;
  int row = gw >> 2;            // b*L + l
  int b = row >> 11, l = row & 2047;
  const u16* src = CKV + (size_t)row * 1024 + kvh * 256;
  u32 p0 = *(const u32*)&src[lane * 2];         // (k,v) for d=lane
  u32 p1 = *(const u32*)&src[(lane + 64) * 2];  // (k,v) for d=lane+64
  float k0 = bf2f((u16)(p0 & 0xffff)), v0 = bf2f((u16)(p0 >> 16));
  float k1 = bf2f((u16)(p1 & 0xffff)), v1 = bf2f((u16)(p1 >> 16));
  float ss = k0 * k0 + k1 * k1;
  for (int off = 1; off < 64; off <<= 1) ss += __shfl_xor(ss, off);
  float scale = rsqrtf(ss * (1.0f / 128.0f) + EPS_);
  size_t kb = (((size_t)b * KVH_ + kvh) * L_ + l) * D_;
  K[kb + lane] = f2bf(k0 * scale * w[lane]);
  K[kb + lane + 64] = f2bf(k1 * scale * w[lane + 64]);
  size_t vb = (((size_t)b * KVH_ + kvh) * D_) * L_ + l;
  Vt[vb + (size_t)lane * L_] = f2bf(v0);
  Vt[vb + (size_t)(lane + 64) * L_] = f2bf(v1);
}

// ---------------- flash attention (no-max softmax) ----------------
// RMSNorm bounds |q·k|*SCALE <= sqrt(128) ~ 11.3, so exp never overflows:
// skip the online max entirely. exp2 scale pre-folded into Q by rmsnorm_q.
// Row sums accumulated per-lane; one shuffle-reduce in the epilogue.
// grid (S/128, H, B), 256 threads. Q-tile 128 rows; KV tiles of 64.
__global__ __launch_bounds__(256, 2) void attn(const u16* __restrict__ Q,
                                               const u16* __restrict__ K,
                                               const u16* __restrict__ Vt,
                                               u16* __restrict__ AO) {
  __shared__ union {
    u16 q[128 * 136];
    struct {
      u16 k[4][64 * 32];                      // [kchunk d/32][l][32]
      u16 v[2][128 * 32];                     // [lchunk l/32][d][32]
      u16 p[4][32 * 72];                      // per-wave P scratch, padded
    } s;
  } sm;
  const int tid = threadIdx.x, wave = tid >> 6, lane = tid & 63;
  const int quad = lane >> 4, l15 = lane & 15;
  const int qt = blockIdx.x, h = blockIdx.y, b = blockIdx.z;
  const int kvh = h >> 2;
  const int s0 = qt * 128;

  // Q tile -> LDS (vectorized), then per-wave A-frags to registers
  const u16* qbase = Q + (size_t)(b * S_ + s0) * HID_ + h * D_;
  for (int it = tid; it < 128 * 16; it += 256) {
    int r = it >> 4, c = (it & 15) * 8;
    *(uint4*)&sm.q[r * 136 + c] = *(const uint4*)&qbase[(size_t)r * HID_ + c];
  }
  __syncthreads();
  const int wr0 = wave * 32;
  bf16x8 qf[2][4];
  for (int i = 0; i < 2; i++)
    for (int kc = 0; kc < 4; kc++)
      qf[i][kc] = *(const bf16x8*)&sm.q[(wr0 + i * 16 + l15) * 136 + kc * 32 + quad * 8];
  __syncthreads();  // Q region now reusable

  float psum[2][4];
  f32x4 o[2][8];
  for (int i = 0; i < 2; i++)
    for (int r = 0; r < 4; r++) psum[i][r] = 0.0f;
  for (int i = 0; i < 2; i++)
    for (int n = 0; n < 8; n++)
      for (int r = 0; r < 4; r++) o[i][n][r] = 0.0f;

  const u16* kbase = K + ((size_t)(b * KVH_ + kvh) * L_) * D_;
  const u16* vbase = Vt + ((size_t)(b * KVH_ + kvh) * D_) * L_;

  for (int l0 = 0; l0 < L_; l0 += 64) {
    // stage K tile: wave w stages k-chunk c=w ([64 l][32 d])
    {
      const u16* kb = kbase + (size_t)l0 * D_ + wave * 32;
      for (int is = 0; is < 4; is++)
        gl2lds16(kb + (size_t)(is * 16 + (lane >> 2)) * D_ + (lane & 3) * 8,
                 &sm.s.k[wave][is * 16 * 32]);
      // stage Vt tile: chunk c=wave>>1, rows (wave&1)*64 + j*16
      const int c = wave >> 1;
      const u16* vb = vbase + l0 + c * 32;
      for (int j = 0; j < 4; j++) {
        int dr = (wave & 1) * 64 + j * 16;
        gl2lds16(vb + (size_t)(dr + (lane >> 2)) * L_ + (lane & 3) * 8,
                 &sm.s.v[c][dr * 32]);
      }
    }
    __syncthreads();

    // S = Q K^T (exp2 scale folded into Q)
    f32x4 sacc[2][4];
    for (int i = 0; i < 2; i++)
      for (int j = 0; j < 4; j++)
        for (int r = 0; r < 4; r++) sacc[i][j][r] = 0.0f;
    for (int j = 0; j < 4; j++) {
      bf16x8 kf[4];
      for (int kc = 0; kc < 4; kc++)
        kf[kc] = *(const bf16x8*)&sm.s.k[kc][(j * 16 + l15) * 32 + quad * 8];
      for (int i = 0; i < 2; i++)
        for (int kc = 0; kc < 4; kc++)
          sacc[i][j] = __builtin_amdgcn_mfma_f32_16x16x32_bf16(qf[i][kc], kf[kc], sacc[i][j], 0, 0, 0);
    }

    // softmax numerator: p = exp2(s), per-lane partial row sums (no max, no rescale)
    for (int i = 0; i < 2; i++) {
      for (int j = 0; j < 4; j++)
        for (int r = 0; r < 4; r++) {
          float p = exp2f(sacc[i][j][r]);
          sacc[i][j][r] = p;
          psum[i][r] += p;
        }
      for (int j = 0; j < 4; j++)
        for (int r = 0; r < 4; r++)
          sm.s.p[wave][(i * 16 + quad * 4 + r) * 72 + j * 16 + l15] = f2bf(sacc[i][j][r]);
    }

    // O += P V  (P via LDS round-trip into A-layout; own-wave region, no barrier)
    for (int kc2 = 0; kc2 < 2; kc2++) {
      bf16x8 pf[2];
      for (int i = 0; i < 2; i++)
        pf[i] = *(const bf16x8*)&sm.s.p[wave][(i * 16 + l15) * 72 + kc2 * 32 + quad * 8];
      for (int n = 0; n < 8; n++) {
        bf16x8 vf = *(const bf16x8*)&sm.s.v[kc2][(n * 16 + l15) * 32 + quad * 8];
        for (int i = 0; i < 2; i++)
          o[i][n] = __builtin_amdgcn_mfma_f32_16x16x32_bf16(pf[i], vf, o[i][n], 0, 0, 0);
      }
    }
    __syncthreads();
  }

  // epilogue: reduce row sums over the 16 col-lanes, O * (1/l) -> AO bf16
  float linv[2][4];
  for (int i = 0; i < 2; i++)
    for (int r = 0; r < 4; r++) {
      float l = psum[i][r];
      for (int off = 1; off < 16; off <<= 1) l += __shfl_xor(l, off);
      linv[i][r] = 1.0f / l;
    }
  u16* obase = AO + (size_t)(b * S_ + s0 + wr0) * HID_ + h * D_;
  for (int i = 0; i < 2; i++)
    for (int n = 0; n < 8; n++)
      for (int r = 0; r < 4; r++) {
        float val = o[i][n][r] * linv[i][r];
        obase[(size_t)(i * 16 + quad * 4 + r) * HID_ + n * 16 + l15] = f2bf(val);
      }
}

// ---------------- launch ----------------
extern "C" void kernel_launch(void* const* d_in, const int* in_sizes, int n_in,
                              void* d_out, int out_size, void* d_ws, size_t ws_size,
                              hipStream_t stream) {
  const float* x = (const float*)d_in[0];
  const float* c = (const float*)d_in[1];
  const float* wq = (const float*)d_in[2];
  const float* wkv = (const float*)d_in[3];
  const float* wo = (const float*)d_in[4];
  const float* nqw = (const float*)d_in[5];
  const float* nkw = (const float*)d_in[6];
  float* out = (float*)d_out;

  const int M = B_ * S_;  // 4096
  char* p = (char*)d_ws;
  auto alloc = [&](size_t bytes) {
    char* r = p;
    p += (bytes + 255) & ~(size_t)255;
    return r;
  };
  u16* xbf = (u16*)alloc((size_t)M * HID_ * 2);          // 16 MB
  u16* cbf = (u16*)alloc((size_t)M * HID_ * 2);          // 16 MB
  u16* wqT = (u16*)alloc((size_t)HID_ * HID_ * 2);       // 8 MB
  u16* wkvT = (u16*)alloc((size_t)1024 * HID_ * 2);      // 4 MB
  u16* woT = (u16*)alloc((size_t)HID_ * HID_ * 2);       // 8 MB
  u16* XQ = (u16*)alloc((size_t)M * HID_ * 2);           // 16 MB
  u16* CKV = (u16*)alloc((size_t)M * 1024 * 2);          // 8 MB
  u16* Kb = (u16*)alloc((size_t)B_ * KVH_ * L_ * D_ * 2);   // 4 MB
  u16* Vt = (u16*)alloc((size_t)B_ * KVH_ * D_ * L_ * 2);   // 4 MB
  u16* AO = (u16*)alloc((size_t)M * HID_ * 2);           // 16 MB

  cvt_bf16<<<8192, 256, 0, stream>>>(x, xbf, M * HID_ / 4);
  cvt_bf16<<<8192, 256, 0, stream>>>(c, cbf, M * HID_ / 4);
  transp_bf16<<<dim3(32, 32), 256, 0, stream>>>(wq, wqT, HID_, HID_);
  transp_bf16<<<dim3(16, 32), 256, 0, stream>>>(wkv, wkvT, HID_, 1024);
  transp_bf16<<<dim3(32, 32), 256, 0, stream>>>(wo, woT, HID_, HID_);
  gemm_bt<u16><<<dim3(32, 16), 256, 0, stream>>>(xbf, wqT, XQ, M, HID_, HID_);
  gemm_bt<u16><<<dim3(32, 8), 256, 0, stream>>>(cbf, wkvT, CKV, M, 1024, HID_);
  rmsnorm_q<<<16384, 256, 0, stream>>>(XQ, nqw);
  knorm_deint<<<4096, 256, 0, stream>>>(CKV, nkw, Kb, Vt);
  attn<<<dim3(16, 16, 2), 256, 0, stream>>>(XQ, Kb, Vt, AO);
  gemm_bt<float><<<dim3(32, 16), 256, 0, stream>>>(AO, woT, out, M, HID_, HID_);
}

// Round 3
// 419.654 us; speedup vs baseline: 1.1396x; 1.0072x over previous
//
#include <hip/hip_runtime.h>

#define B_ 2
#define S_ 2048
#define L_ 2048
#define H_ 16
#define KVH_ 4
#define D_ 128
#define HID_ 2048
#define EPS_ 1e-6f

typedef unsigned short u16;
typedef unsigned int u32;
typedef __bf16 bf16x8 __attribute__((ext_vector_type(8)));
typedef float f32x4 __attribute__((ext_vector_type(4)));
typedef unsigned u32x2v __attribute__((ext_vector_type(2)));
typedef unsigned u32x4v __attribute__((ext_vector_type(4)));

__device__ __forceinline__ float bf2f(u32 u) {
  union { u32 i; float f; } x; x.i = u << 16; return x.f;
}
__device__ __forceinline__ u16 f2bf(float f) {
  union { float f; u32 i; } x; x.f = f;
  return (u16)((x.i + 0x7fffu + ((x.i >> 16) & 1u)) >> 16);
}
__device__ __forceinline__ u32 pack_bf16(float a, float b) {
#if __has_builtin(__builtin_amdgcn_cvt_pk_bf16_f32)
  typedef __bf16 bf16x2 __attribute__((ext_vector_type(2)));
  union { bf16x2 v; u32 u; } c;
  c.v = __builtin_amdgcn_cvt_pk_bf16_f32(a, b);
  return c.u;
#else
  return (u32)f2bf(a) | ((u32)f2bf(b) << 16);
#endif
}
// async global->LDS, 16B per lane. LDS dest = wave-uniform base + lane*16.
__device__ __forceinline__ void gl2lds16(const u16* g, u16* l) {
  __builtin_amdgcn_global_load_lds(
      (const __attribute__((address_space(1))) u32*)g,
      (__attribute__((address_space(3))) u32*)l, 16, 0, 0);
}

#if __has_builtin(__builtin_amdgcn_permlane32_swap) && __has_builtin(__builtin_amdgcn_permlane16_swap)
#define HAS_PLS 1
#else
#define HAS_PLS 0
#endif

// MFMA C-layout (2 16x16 tiles, packed bf16 pairs) -> one K=32 A-frag.
// xa/xb = low/high reg-pairs of tile covering k 0-15; ya/yb = tile k 16-31.
__device__ __forceinline__ u32x4v ctoa(u32 xa, u32 xb, u32 ya, u32 yb,
                                       int quad, int l15) {
  u32x4v f;
#if HAS_PLS
  u32x2v t1 = __builtin_amdgcn_permlane32_swap(xa, ya, false, false);
  u32x2v t2 = __builtin_amdgcn_permlane16_swap(t1.x, t1.y, false, false);
  u32x2v t3 = __builtin_amdgcn_permlane32_swap(xb, yb, false, false);
  u32x2v t4 = __builtin_amdgcn_permlane16_swap(t3.x, t3.y, false, false);
  f.x = t2.x; f.y = t4.x; f.z = t2.y; f.w = t4.y;
#else
  int a0 = (((2 * quad) & 3) * 16 + l15) << 2;
  int a1 = (((2 * quad + 1) & 3) * 16 + l15) << 2;
  u32 xa0 = __builtin_amdgcn_ds_bpermute(a0, xa), ya0 = __builtin_amdgcn_ds_bpermute(a0, ya);
  u32 xb0 = __builtin_amdgcn_ds_bpermute(a0, xb), yb0 = __builtin_amdgcn_ds_bpermute(a0, yb);
  u32 xa1 = __builtin_amdgcn_ds_bpermute(a1, xa), ya1 = __builtin_amdgcn_ds_bpermute(a1, ya);
  u32 xb1 = __builtin_amdgcn_ds_bpermute(a1, xb), yb1 = __builtin_amdgcn_ds_bpermute(a1, yb);
  bool hi = quad >= 2;
  f.x = hi ? ya0 : xa0; f.y = hi ? yb0 : xb0;
  f.z = hi ? ya1 : xa1; f.w = hi ? yb1 : xb1;
#endif
  return f;
}

// ---------------- elementwise fp32 -> bf16 cast ----------------
__global__ __launch_bounds__(256) void cvt_bf16(const float* __restrict__ in,
                                                u16* __restrict__ out, int n4) {
  int i = blockIdx.x * 256 + threadIdx.x;
  if (i >= n4) return;
  float4 v = ((const float4*)in)[i];
  uint2 o;
  o.x = pack_bf16(v.x, v.y);
  o.y = pack_bf16(v.z, v.w);
  ((uint2*)out)[i] = o;
}

// ---------------- LDS-tiled transpose fp32[R][C] -> bf16[C][R] ----------------
__global__ __launch_bounds__(256) void transp_bf16(const float* __restrict__ A,
                                                   u16* __restrict__ At, int R, int C) {
  __shared__ float t[64][65];
  int c0 = blockIdx.x * 64, r0 = blockIdx.y * 64;
  int tx = threadIdx.x & 63, ty = threadIdx.x >> 6;
  for (int i = ty; i < 64; i += 4)
    t[i][tx] = A[(size_t)(r0 + i) * C + c0 + tx];
  __syncthreads();
  for (int i = ty; i < 64; i += 4)
    At[(size_t)(c0 + i) * R + r0 + tx] = f2bf(t[tx][i]);
}

// ---------------- bf16 GEMM: C[M][N] = A[M][K] @ Bt[N][K]^T ----------------
__device__ __forceinline__ void store_out(u16* p, float v) { *p = f2bf(v); }
__device__ __forceinline__ void store_out(float* p, float v) { *p = v; }

template <typename OutT>
__global__ __launch_bounds__(256, 2) void gemm_bt(const u16* __restrict__ A,
                                                  const u16* __restrict__ Bt,
                                                  OutT* __restrict__ C,
                                                  int M, int N, int K) {
  __shared__ u16 sA[128 * 32];
  __shared__ u16 sB[128 * 32];
  const int tid = threadIdx.x;
  const int wave = tid >> 6, lane = tid & 63;
  const int quad = lane >> 4, l15 = lane & 15;
  const int m0 = blockIdx.x * 128, n0 = blockIdx.y * 128;
  const int wm = (wave >> 1) * 64, wn = (wave & 1) * 64;
  const u16* aP = A + (size_t)m0 * K;
  const u16* bP = Bt + (size_t)n0 * K;
  const int sr = lane >> 2;
  const int sc = (lane & 3) * 8;
  const int r0 = wave * 32, r1 = wave * 32 + 16;

  f32x4 acc[4][4];
  for (int i = 0; i < 4; i++)
    for (int j = 0; j < 4; j++)
      for (int r = 0; r < 4; r++) acc[i][j][r] = 0.0f;

  for (int k0 = 0; k0 < K; k0 += 32) {
    gl2lds16(aP + (size_t)(r0 + sr) * K + k0 + sc, &sA[r0 * 32]);
    gl2lds16(aP + (size_t)(r1 + sr) * K + k0 + sc, &sA[r1 * 32]);
    gl2lds16(bP + (size_t)(r0 + sr) * K + k0 + sc, &sB[r0 * 32]);
    gl2lds16(bP + (size_t)(r1 + sr) * K + k0 + sc, &sB[r1 * 32]);
    __syncthreads();
    bf16x8 afrag[4], bfrag[4];
    for (int i = 0; i < 4; i++)
      afrag[i] = *(const bf16x8*)&sA[(wm + i * 16 + l15) * 32 + quad * 8];
    for (int j = 0; j < 4; j++)
      bfrag[j] = *(const bf16x8*)&sB[(wn + j * 16 + l15) * 32 + quad * 8];
    for (int i = 0; i < 4; i++)
      for (int j = 0; j < 4; j++)
        acc[i][j] = __builtin_amdgcn_mfma_f32_16x16x32_bf16(afrag[i], bfrag[j], acc[i][j], 0, 0, 0);
    __syncthreads();
  }
  for (int i = 0; i < 4; i++)
    for (int j = 0; j < 4; j++) {
      int row = m0 + wm + i * 16 + quad * 4;
      int col = n0 + wn + j * 16 + l15;
      for (int r = 0; r < 4; r++)
        store_out(&C[(size_t)(row + r) * N + col], acc[i][j][r]);
    }
}

// ---------------- per-head RMSNorm on Q, in place (bf16) ----------------
// Folds SCALE*log2(e) so attn can use exp2 directly.
__global__ __launch_bounds__(256) void rmsnorm_q(u16* __restrict__ XQ,
                                                 const float* __restrict__ w) {
  int gw = blockIdx.x * 4 + (threadIdx.x >> 6);
  int lane = threadIdx.x & 63;
  u16* base = XQ + (size_t)gw * 128;
  float x0 = bf2f(base[lane]), x1 = bf2f(base[lane + 64]);
  float ss = x0 * x0 + x1 * x1;
  for (int off = 1; off < 64; off <<= 1) ss += __shfl_xor(ss, off);
  const float cexp = 0.12753102331322172f;  // (1/sqrt(128)) * log2(e)
  float scale = rsqrtf(ss * (1.0f / 128.0f) + EPS_) * cexp;
  base[lane] = f2bf(x0 * scale * w[lane]);
  base[lane + 64] = f2bf(x1 * scale * w[lane + 64]);
}

// ---------------- K-norm + deinterleave CKV -> K, V^T (coalesced) ----------------
// grid (L/64, KVH, B). Vt written via LDS transpose -> u32 coalesced stores.
__global__ __launch_bounds__(256) void knorm_deint(const u16* __restrict__ CKV,
                                                   const float* __restrict__ w,
                                                   u16* __restrict__ K,
                                                   u16* __restrict__ Vt) {
  __shared__ u16 vbuf[128][66];
  const int tid = threadIdx.x, wave = tid >> 6, lane = tid & 63;
  const int l0 = blockIdx.x * 64, kvh = blockIdx.y, b = blockIdx.z;
  for (int it = 0; it < 16; it++) {
    int ll = wave * 16 + it;
    int row = b * L_ + l0 + ll;
    const u16* src = CKV + (size_t)row * 1024 + kvh * 256;
    u32 p0 = *(const u32*)&src[lane * 2];
    u32 p1 = *(const u32*)&src[(lane + 64) * 2];
    float k0 = bf2f(p0 & 0xffff), v0 = bf2f(p0 >> 16);
    float k1 = bf2f(p1 & 0xffff), v1 = bf2f(p1 >> 16);
    float ss = k0 * k0 + k1 * k1;
    for (int off = 1; off < 64; off <<= 1) ss += __shfl_xor(ss, off);
    float sc = rsqrtf(ss * (1.0f / 128.0f) + EPS_);
    size_t kb = (((size_t)b * KVH_ + kvh) * L_ + l0 + ll) * D_;
    K[kb + lane] = f2bf(k0 * sc * w[lane]);
    K[kb + lane + 64] = f2bf(k1 * sc * w[lane + 64]);
    vbuf[lane][ll] = f2bf(v0);
    vbuf[lane + 64][ll] = f2bf(v1);
  }
  __syncthreads();
  for (int it = tid; it < 128 * 32; it += 256) {
    int d = it >> 5, cc = (it & 31) * 2;
    u32 pk = (u32)vbuf[d][cc] | ((u32)vbuf[d][cc + 1] << 16);
    *(u32*)&Vt[(((size_t)b * KVH_ + kvh) * D_ + d) * L_ + l0 + cc] = pk;
  }
}

// ---------------- flash attention (no-max softmax, register P) ----------------
// St = K·Q^T so P emerges lane-aligned for PV; C->A via permlane swaps.
// Q-tile 64 rows (grid 1024 -> 4 blocks/CU), KV-tile 64, LDS 32 KB.
__global__ __launch_bounds__(256, 4) void attn(const u16* __restrict__ Q,
                                               const u16* __restrict__ K,
                                               const u16* __restrict__ Vt,
                                               u16* __restrict__ AO) {
  __shared__ u16 sk[4][64 * 32];   // [d-chunk][l-row][32 d]
  __shared__ u16 sv[2][128 * 32];  // [l-chunk][d-row][32 l]
  const int tid = threadIdx.x, wave = tid >> 6, lane = tid & 63;
  const int quad = lane >> 4, l15 = lane & 15;
  const int qt = blockIdx.x, h = blockIdx.y, b = blockIdx.z;
  const int kvh = h >> 2;
  const int s0 = qt * 64, wr0 = wave * 16;

  // Q frags straight from global (one-time, 4x16B per lane)
  const u16* qrow = Q + (size_t)(b * S_ + s0 + wr0 + l15) * HID_ + h * D_;
  bf16x8 qf[4];
  for (int kc = 0; kc < 4; kc++)
    qf[kc] = *(const bf16x8*)&qrow[kc * 32 + quad * 8];

  float psum = 0.0f;
  f32x4 o[8];
  for (int n = 0; n < 8; n++)
    for (int r = 0; r < 4; r++) o[n][r] = 0.0f;

  const u16* kbase = K + ((size_t)(b * KVH_ + kvh) * L_) * D_;
  const u16* vbase = Vt + ((size_t)(b * KVH_ + kvh) * D_) * L_;
  const int srow = lane >> 2, scol = (lane & 3) * 8;

  for (int l0 = 0; l0 < L_; l0 += 64) {
    const u16* kb = kbase + (size_t)l0 * D_ + wave * 32;
    for (int is = 0; is < 4; is++)
      gl2lds16(kb + (size_t)(is * 16 + srow) * D_ + scol, &sk[wave][is * 16 * 32]);
    const int c = wave >> 1;
    const u16* vb = vbase + l0 + c * 32;
    for (int j = 0; j < 4; j++) {
      int dr = (wave & 1) * 64 + j * 16;
      gl2lds16(vb + (size_t)(dr + srow) * L_ + scol, &sv[c][dr * 32]);
    }
    __syncthreads();

    // St[l][q] = K·Q^T : lane=q (col), regs=l
    f32x4 sacc[4];
    for (int j = 0; j < 4; j++)
      for (int r = 0; r < 4; r++) sacc[j][r] = 0.0f;
    for (int j = 0; j < 4; j++)
      for (int kc = 0; kc < 4; kc++) {
        bf16x8 kf = *(const bf16x8*)&sk[kc][(j * 16 + l15) * 32 + quad * 8];
        sacc[j] = __builtin_amdgcn_mfma_f32_16x16x32_bf16(kf, qf[kc], sacc[j], 0, 0, 0);
      }

    // p = exp2(s) (scale pre-folded into Q); per-lane partial row sum
    u32 pa[4], pb[4];
    for (int j = 0; j < 4; j++) {
      float p0 = exp2f(sacc[j][0]), p1 = exp2f(sacc[j][1]);
      float p2 = exp2f(sacc[j][2]), p3 = exp2f(sacc[j][3]);
      psum += (p0 + p1) + (p2 + p3);
      pa[j] = pack_bf16(p0, p1);
      pb[j] = pack_bf16(p2, p3);
    }

    // O += P V : P C-frags -> A-frags in registers, no LDS
    for (int cc = 0; cc < 2; cc++) {
      union { u32x4v u; bf16x8 v; } pf;
      pf.u = ctoa(pa[2 * cc], pb[2 * cc], pa[2 * cc + 1], pb[2 * cc + 1], quad, l15);
      for (int n = 0; n < 8; n++) {
        bf16x8 vf = *(const bf16x8*)&sv[cc][(n * 16 + l15) * 32 + quad * 8];
        o[n] = __builtin_amdgcn_mfma_f32_16x16x32_bf16(pf.v, vf, o[n], 0, 0, 0);
      }
    }
    __syncthreads();
  }

  // epilogue: reduce psum across quads (lane=q replicated), scale, store
  psum += __shfl_xor(psum, 16);
  psum += __shfl_xor(psum, 32);
  float linv = 1.0f / psum;
  float lr[4];
  for (int r = 0; r < 4; r++) lr[r] = __shfl(linv, quad * 4 + r);
  u16* ob = AO + (size_t)(b * S_ + s0 + wr0) * HID_ + h * D_;
  for (int n = 0; n < 8; n++)
    for (int r = 0; r < 4; r++)
      ob[(size_t)(quad * 4 + r) * HID_ + n * 16 + l15] = f2bf(o[n][r] * lr[r]);
}

// ---------------- launch ----------------
extern "C" void kernel_launch(void* const* d_in, const int* in_sizes, int n_in,
                              void* d_out, int out_size, void* d_ws, size_t ws_size,
                              hipStream_t stream) {
  const float* x = (const float*)d_in[0];
  const float* c = (const float*)d_in[1];
  const float* wq = (const float*)d_in[2];
  const float* wkv = (const float*)d_in[3];
  const float* wo = (const float*)d_in[4];
  const float* nqw = (const float*)d_in[5];
  const float* nkw = (const float*)d_in[6];
  float* out = (float*)d_out;

  const int M = B_ * S_;  // 4096
  char* p = (char*)d_ws;
  auto alloc = [&](size_t bytes) {
    char* r = p;
    p += (bytes + 255) & ~(size_t)255;
    return r;
  };
  u16* xbf = (u16*)alloc((size_t)M * HID_ * 2);
  u16* cbf = (u16*)alloc((size_t)M * HID_ * 2);
  u16* wqT = (u16*)alloc((size_t)HID_ * HID_ * 2);
  u16* wkvT = (u16*)alloc((size_t)1024 * HID_ * 2);
  u16* woT = (u16*)alloc((size_t)HID_ * HID_ * 2);
  u16* XQ = (u16*)alloc((size_t)M * HID_ * 2);
  u16* CKV = (u16*)alloc((size_t)M * 1024 * 2);
  u16* Kb = (u16*)alloc((size_t)B_ * KVH_ * L_ * D_ * 2);
  u16* Vt = (u16*)alloc((size_t)B_ * KVH_ * D_ * L_ * 2);
  u16* AO = (u16*)alloc((size_t)M * HID_ * 2);

  cvt_bf16<<<8192, 256, 0, stream>>>(x, xbf, M * HID_ / 4);
  cvt_bf16<<<8192, 256, 0, stream>>>(c, cbf, M * HID_ / 4);
  transp_bf16<<<dim3(32, 32), 256, 0, stream>>>(wq, wqT, HID_, HID_);
  transp_bf16<<<dim3(16, 32), 256, 0, stream>>>(wkv, wkvT, HID_, 1024);
  transp_bf16<<<dim3(32, 32), 256, 0, stream>>>(wo, woT, HID_, HID_);
  gemm_bt<u16><<<dim3(32, 16), 256, 0, stream>>>(xbf, wqT, XQ, M, HID_, HID_);
  gemm_bt<u16><<<dim3(32, 8), 256, 0, stream>>>(cbf, wkvT, CKV, M, 1024, HID_);
  rmsnorm_q<<<16384, 256, 0, stream>>>(XQ, nqw);
  knorm_deint<<<dim3(32, 4, 2), 256, 0, stream>>>(CKV, nkw, Kb, Vt);
  attn<<<dim3(32, 16, 2), 256, 0, stream>>>(XQ, Kb, Vt, AO);
  gemm_bt<float><<<dim3(32, 16), 256, 0, stream>>>(AO, woT, out, M, HID_, HID_);
}

// Round 4
// 401.156 us; speedup vs baseline: 1.1921x; 1.0461x over previous
//
#include <hip/hip_runtime.h>

#define B_ 2
#define S_ 2048
#define L_ 2048
#define H_ 16
#define KVH_ 4
#define D_ 128
#define HID_ 2048
#define EPS_ 1e-6f

typedef unsigned short u16;
typedef unsigned int u32;
typedef __bf16 bf16x8 __attribute__((ext_vector_type(8)));
typedef float f32x4 __attribute__((ext_vector_type(4)));
typedef unsigned u32x2v __attribute__((ext_vector_type(2)));
typedef unsigned u32x4v __attribute__((ext_vector_type(4)));

__device__ __forceinline__ float bf2f(u32 u) {
  union { u32 i; float f; } x; x.i = u << 16; return x.f;
}
__device__ __forceinline__ u16 f2bf(float f) {
  union { float f; u32 i; } x; x.f = f;
  return (u16)((x.i + 0x7fffu + ((x.i >> 16) & 1u)) >> 16);
}
__device__ __forceinline__ u32 pack_bf16(float a, float b) {
#if __has_builtin(__builtin_amdgcn_cvt_pk_bf16_f32)
  typedef __bf16 bf16x2 __attribute__((ext_vector_type(2)));
  union { bf16x2 v; u32 u; } c;
  c.v = __builtin_amdgcn_cvt_pk_bf16_f32(a, b);
  return c.u;
#else
  return (u32)f2bf(a) | ((u32)f2bf(b) << 16);
#endif
}
// async global->LDS, 16B per lane. LDS dest = wave-uniform base + lane*16.
__device__ __forceinline__ void gl2lds16(const u16* g, u16* l) {
  __builtin_amdgcn_global_load_lds(
      (const __attribute__((address_space(1))) u32*)g,
      (__attribute__((address_space(3))) u32*)l, 16, 0, 0);
}

#if __has_builtin(__builtin_amdgcn_permlane32_swap) && __has_builtin(__builtin_amdgcn_permlane16_swap)
#define HAS_PLS 1
#else
#define HAS_PLS 0
#endif

// MFMA C-layout (2 16x16 tiles, packed bf16 pairs) -> one K=32 A-frag.
__device__ __forceinline__ u32x4v ctoa(u32 xa, u32 xb, u32 ya, u32 yb,
                                       int quad, int l15) {
  u32x4v f;
#if HAS_PLS
  u32x2v t1 = __builtin_amdgcn_permlane32_swap(xa, ya, false, false);
  u32x2v t2 = __builtin_amdgcn_permlane16_swap(t1.x, t1.y, false, false);
  u32x2v t3 = __builtin_amdgcn_permlane32_swap(xb, yb, false, false);
  u32x2v t4 = __builtin_amdgcn_permlane16_swap(t3.x, t3.y, false, false);
  f.x = t2.x; f.y = t4.x; f.z = t2.y; f.w = t4.y;
#else
  int a0 = (((2 * quad) & 3) * 16 + l15) << 2;
  int a1 = (((2 * quad + 1) & 3) * 16 + l15) << 2;
  u32 xa0 = __builtin_amdgcn_ds_bpermute(a0, xa), ya0 = __builtin_amdgcn_ds_bpermute(a0, ya);
  u32 xb0 = __builtin_amdgcn_ds_bpermute(a0, xb), yb0 = __builtin_amdgcn_ds_bpermute(a0, yb);
  u32 xa1 = __builtin_amdgcn_ds_bpermute(a1, xa), ya1 = __builtin_amdgcn_ds_bpermute(a1, ya);
  u32 xb1 = __builtin_amdgcn_ds_bpermute(a1, xb), yb1 = __builtin_amdgcn_ds_bpermute(a1, yb);
  bool hi = quad >= 2;
  f.x = hi ? ya0 : xa0; f.y = hi ? yb0 : xb0;
  f.z = hi ? ya1 : xa1; f.w = hi ? yb1 : xb1;
#endif
  return f;
}

// ---------------- elementwise fp32 -> bf16 cast ----------------
__global__ __launch_bounds__(256) void cvt_bf16(const float* __restrict__ in,
                                                u16* __restrict__ out, int n4) {
  int i = blockIdx.x * 256 + threadIdx.x;
  if (i >= n4) return;
  float4 v = ((const float4*)in)[i];
  uint2 o;
  o.x = pack_bf16(v.x, v.y);
  o.y = pack_bf16(v.z, v.w);
  ((uint2*)out)[i] = o;
}

// ---------------- LDS-tiled transpose fp32[R][C] -> bf16[C][R] ----------------
__global__ __launch_bounds__(256) void transp_bf16(const float* __restrict__ A,
                                                   u16* __restrict__ At, int R, int C) {
  __shared__ float t[64][65];
  int c0 = blockIdx.x * 64, r0 = blockIdx.y * 64;
  int tx = threadIdx.x & 63, ty = threadIdx.x >> 6;
  for (int i = ty; i < 64; i += 4)
    t[i][tx] = A[(size_t)(r0 + i) * C + c0 + tx];
  __syncthreads();
  for (int i = ty; i < 64; i += 4)
    At[(size_t)(c0 + i) * R + r0 + tx] = f2bf(t[tx][i]);
}

// ---------------- bf16 GEMM: C[M][N] = A[M][K] @ Bt[N][K]^T ----------------
__device__ __forceinline__ void store_out(u16* p, float v) { *p = f2bf(v); }
__device__ __forceinline__ void store_out(float* p, float v) { *p = v; }

template <typename OutT>
__global__ __launch_bounds__(256, 2) void gemm_bt(const u16* __restrict__ A,
                                                  const u16* __restrict__ Bt,
                                                  OutT* __restrict__ C,
                                                  int M, int N, int K) {
  __shared__ u16 sA[128 * 32];
  __shared__ u16 sB[128 * 32];
  const int tid = threadIdx.x;
  const int wave = tid >> 6, lane = tid & 63;
  const int quad = lane >> 4, l15 = lane & 15;
  const int m0 = blockIdx.x * 128, n0 = blockIdx.y * 128;
  const int wm = (wave >> 1) * 64, wn = (wave & 1) * 64;
  const u16* aP = A + (size_t)m0 * K;
  const u16* bP = Bt + (size_t)n0 * K;
  const int sr = lane >> 2;
  const int sc = (lane & 3) * 8;
  const int r0 = wave * 32, r1 = wave * 32 + 16;

  f32x4 acc[4][4];
  for (int i = 0; i < 4; i++)
    for (int j = 0; j < 4; j++)
      for (int r = 0; r < 4; r++) acc[i][j][r] = 0.0f;

  for (int k0 = 0; k0 < K; k0 += 32) {
    gl2lds16(aP + (size_t)(r0 + sr) * K + k0 + sc, &sA[r0 * 32]);
    gl2lds16(aP + (size_t)(r1 + sr) * K + k0 + sc, &sA[r1 * 32]);
    gl2lds16(bP + (size_t)(r0 + sr) * K + k0 + sc, &sB[r0 * 32]);
    gl2lds16(bP + (size_t)(r1 + sr) * K + k0 + sc, &sB[r1 * 32]);
    __syncthreads();
    bf16x8 afrag[4], bfrag[4];
    for (int i = 0; i < 4; i++)
      afrag[i] = *(const bf16x8*)&sA[(wm + i * 16 + l15) * 32 + quad * 8];
    for (int j = 0; j < 4; j++)
      bfrag[j] = *(const bf16x8*)&sB[(wn + j * 16 + l15) * 32 + quad * 8];
    for (int i = 0; i < 4; i++)
      for (int j = 0; j < 4; j++)
        acc[i][j] = __builtin_amdgcn_mfma_f32_16x16x32_bf16(afrag[i], bfrag[j], acc[i][j], 0, 0, 0);
    __syncthreads();
  }
  for (int i = 0; i < 4; i++)
    for (int j = 0; j < 4; j++) {
      int row = m0 + wm + i * 16 + quad * 4;
      int col = n0 + wn + j * 16 + l15;
      for (int r = 0; r < 4; r++)
        store_out(&C[(size_t)(row + r) * N + col], acc[i][j][r]);
    }
}

// ---------------- K-norm + deinterleave CKV -> K, V^T (coalesced) ----------------
__global__ __launch_bounds__(256) void knorm_deint(const u16* __restrict__ CKV,
                                                   const float* __restrict__ w,
                                                   u16* __restrict__ K,
                                                   u16* __restrict__ Vt) {
  __shared__ u16 vbuf[128][66];
  const int tid = threadIdx.x, wave = tid >> 6, lane = tid & 63;
  const int l0 = blockIdx.x * 64, kvh = blockIdx.y, b = blockIdx.z;
  for (int it = 0; it < 16; it++) {
    int ll = wave * 16 + it;
    int row = b * L_ + l0 + ll;
    const u16* src = CKV + (size_t)row * 1024 + kvh * 256;
    u32 p0 = *(const u32*)&src[lane * 2];
    u32 p1 = *(const u32*)&src[(lane + 64) * 2];
    float k0 = bf2f(p0 & 0xffff), v0 = bf2f(p0 >> 16);
    float k1 = bf2f(p1 & 0xffff), v1 = bf2f(p1 >> 16);
    float ss = k0 * k0 + k1 * k1;
    for (int off = 1; off < 64; off <<= 1) ss += __shfl_xor(ss, off);
    float sc = rsqrtf(ss * (1.0f / 128.0f) + EPS_);
    size_t kb = (((size_t)b * KVH_ + kvh) * L_ + l0 + ll) * D_;
    K[kb + lane] = f2bf(k0 * sc * w[lane]);
    K[kb + lane + 64] = f2bf(k1 * sc * w[lane + 64]);
    vbuf[lane][ll] = f2bf(v0);
    vbuf[lane + 64][ll] = f2bf(v1);
  }
  __syncthreads();
  for (int it = tid; it < 128 * 32; it += 256) {
    int d = it >> 5, cc = (it & 31) * 2;
    u32 pk = (u32)vbuf[d][cc] | ((u32)vbuf[d][cc + 1] << 16);
    *(u32*)&Vt[(((size_t)b * KVH_ + kvh) * D_ + d) * L_ + l0 + cc] = pk;
  }
}

// ---------------- flash attention ----------------
// Q-tile 128 (wave owns 32 q-rows: every kf/vf LDS read feeds 2 MFMAs),
// KV-tile 128 (half the barriers), register P via permlane ctoa,
// per-head Q-RMSNorm fused into the one-time Q load (scale*log2e folded).
__global__ __launch_bounds__(256, 2) void attn(const u16* __restrict__ XQ,
                                               const float* __restrict__ nw,
                                               const u16* __restrict__ K,
                                               const u16* __restrict__ Vt,
                                               u16* __restrict__ AO) {
  __shared__ u16 sk[4][128 * 32];  // [d-chunk][l-row][32 d]
  __shared__ u16 sv[4][128 * 32];  // [l-chunk][d-row][32 l]
  const int tid = threadIdx.x, wave = tid >> 6, lane = tid & 63;
  const int quad = lane >> 4, l15 = lane & 15;
  const int qt = blockIdx.x, h = blockIdx.y, b = blockIdx.z;
  const int kvh = h >> 2;
  const int s0 = qt * 128, wr0 = wave * 32;

  // ---- one-time: load 32 q-rows, fused RMSNorm (+SCALE*log2e), to A-frags ----
  bf16x8 qf[2][4];
  {
    const float cexp = 0.12753102331322172f;  // (1/sqrt(128)) * log2(e)
    const u16* qrow = XQ + (size_t)(b * S_ + s0 + wr0 + l15) * HID_ + h * D_;
    for (int i = 0; i < 2; i++) {
      const u16* qr = qrow + (size_t)i * 16 * HID_;
      float vals[4][8];
      float ss = 0.0f;
      for (int kc = 0; kc < 4; kc++) {
        uint4 u = *(const uint4*)&qr[kc * 32 + quad * 8];
        u32 uu[4] = {u.x, u.y, u.z, u.w};
        for (int e = 0; e < 4; e++) {
          float lo = bf2f(uu[e] & 0xffff), hi = bf2f(uu[e] >> 16);
          vals[kc][2 * e] = lo;
          vals[kc][2 * e + 1] = hi;
          ss += lo * lo + hi * hi;
        }
      }
      ss += __shfl_xor(ss, 16);
      ss += __shfl_xor(ss, 32);
      float scale = rsqrtf(ss * (1.0f / 128.0f) + EPS_) * cexp;
      for (int kc = 0; kc < 4; kc++) {
        float4 w0 = *(const float4*)&nw[kc * 32 + quad * 8];
        float4 w1 = *(const float4*)&nw[kc * 32 + quad * 8 + 4];
        union { u32x4v u; bf16x8 v; } q;
        q.u.x = pack_bf16(vals[kc][0] * scale * w0.x, vals[kc][1] * scale * w0.y);
        q.u.y = pack_bf16(vals[kc][2] * scale * w0.z, vals[kc][3] * scale * w0.w);
        q.u.z = pack_bf16(vals[kc][4] * scale * w1.x, vals[kc][5] * scale * w1.y);
        q.u.w = pack_bf16(vals[kc][6] * scale * w1.z, vals[kc][7] * scale * w1.w);
        qf[i][kc] = q.v;
      }
    }
  }

  float psum[2] = {0.0f, 0.0f};
  f32x4 o[2][8];
  for (int i = 0; i < 2; i++)
    for (int n = 0; n < 8; n++)
      for (int r = 0; r < 4; r++) o[i][n][r] = 0.0f;

  const u16* kbase = K + ((size_t)(b * KVH_ + kvh) * L_) * D_;
  const u16* vbase = Vt + ((size_t)(b * KVH_ + kvh) * D_) * L_;
  const int srow = lane >> 2, scol = (lane & 3) * 8;

  for (int l0 = 0; l0 < L_; l0 += 128) {
    // stage K (wave stages d-chunk=wave) and V^T (wave stages l-chunk=wave)
    const u16* kb = kbase + (size_t)l0 * D_ + wave * 32;
    for (int is = 0; is < 8; is++)
      gl2lds16(kb + (size_t)(is * 16 + srow) * D_ + scol, &sk[wave][is * 16 * 32]);
    const u16* vb = vbase + l0 + wave * 32;
    for (int is = 0; is < 8; is++)
      gl2lds16(vb + (size_t)(is * 16 + srow) * L_ + scol, &sv[wave][is * 16 * 32]);
    __syncthreads();

    for (int cc = 0; cc < 4; cc++) {
      // St = K·Q^T for l-sub pair (2cc, 2cc+1) x both q-subs
      f32x4 sacc[2][2];
      for (int jj = 0; jj < 2; jj++)
        for (int i = 0; i < 2; i++)
          for (int r = 0; r < 4; r++) sacc[jj][i][r] = 0.0f;
      for (int jj = 0; jj < 2; jj++) {
        int j = cc * 2 + jj;
        for (int kc = 0; kc < 4; kc++) {
          bf16x8 kf = *(const bf16x8*)&sk[kc][(j * 16 + l15) * 32 + quad * 8];
          for (int i = 0; i < 2; i++)
            sacc[jj][i] = __builtin_amdgcn_mfma_f32_16x16x32_bf16(kf, qf[i][kc], sacc[jj][i], 0, 0, 0);
        }
      }
      // p = exp2(s); per-lane partial row sums; pack + C->A in registers
      union { u32x4v u; bf16x8 v; } pf[2];
      for (int i = 0; i < 2; i++) {
        float p0[4], p1[4];
        for (int r = 0; r < 4; r++) {
          p0[r] = exp2f(sacc[0][i][r]);
          p1[r] = exp2f(sacc[1][i][r]);
          psum[i] += p0[r] + p1[r];
        }
        u32 xa = pack_bf16(p0[0], p0[1]), xb = pack_bf16(p0[2], p0[3]);
        u32 ya = pack_bf16(p1[0], p1[1]), yb = pack_bf16(p1[2], p1[3]);
        pf[i].u = ctoa(xa, xb, ya, yb, quad, l15);
      }
      // O += P V for this 32-l chunk
      for (int n = 0; n < 8; n++) {
        bf16x8 vf = *(const bf16x8*)&sv[cc][(n * 16 + l15) * 32 + quad * 8];
        for (int i = 0; i < 2; i++)
          o[i][n] = __builtin_amdgcn_mfma_f32_16x16x32_bf16(pf[i].v, vf, o[i][n], 0, 0, 0);
      }
    }
    __syncthreads();
  }

  // epilogue: reduce psum across quads (lane=q replicated), scale, store
  for (int i = 0; i < 2; i++) {
    float s = psum[i];
    s += __shfl_xor(s, 16);
    s += __shfl_xor(s, 32);
    float linv = 1.0f / s;
    float lr[4];
    for (int r = 0; r < 4; r++) lr[r] = __shfl(linv, quad * 4 + r);
    u16* ob = AO + (size_t)(b * S_ + s0 + wr0 + i * 16) * HID_ + h * D_;
    for (int n = 0; n < 8; n++)
      for (int r = 0; r < 4; r++)
        ob[(size_t)(quad * 4 + r) * HID_ + n * 16 + l15] = f2bf(o[i][n][r] * lr[r]);
  }
}

// ---------------- launch ----------------
extern "C" void kernel_launch(void* const* d_in, const int* in_sizes, int n_in,
                              void* d_out, int out_size, void* d_ws, size_t ws_size,
                              hipStream_t stream) {
  const float* x = (const float*)d_in[0];
  const float* c = (const float*)d_in[1];
  const float* wq = (const float*)d_in[2];
  const float* wkv = (const float*)d_in[3];
  const float* wo = (const float*)d_in[4];
  const float* nqw = (const float*)d_in[5];
  const float* nkw = (const float*)d_in[6];
  float* out = (float*)d_out;

  const int M = B_ * S_;  // 4096
  char* p = (char*)d_ws;
  auto alloc = [&](size_t bytes) {
    char* r = p;
    p += (bytes + 255) & ~(size_t)255;
    return r;
  };
  u16* xbf = (u16*)alloc((size_t)M * HID_ * 2);
  u16* cbf = (u16*)alloc((size_t)M * HID_ * 2);
  u16* wqT = (u16*)alloc((size_t)HID_ * HID_ * 2);
  u16* wkvT = (u16*)alloc((size_t)1024 * HID_ * 2);
  u16* woT = (u16*)alloc((size_t)HID_ * HID_ * 2);
  u16* XQ = (u16*)alloc((size_t)M * HID_ * 2);
  u16* CKV = (u16*)alloc((size_t)M * 1024 * 2);
  u16* Kb = (u16*)alloc((size_t)B_ * KVH_ * L_ * D_ * 2);
  u16* Vt = (u16*)alloc((size_t)B_ * KVH_ * D_ * L_ * 2);
  u16* AO = (u16*)alloc((size_t)M * HID_ * 2);

  cvt_bf16<<<8192, 256, 0, stream>>>(x, xbf, M * HID_ / 4);
  cvt_bf16<<<8192, 256, 0, stream>>>(c, cbf, M * HID_ / 4);
  transp_bf16<<<dim3(32, 32), 256, 0, stream>>>(wq, wqT, HID_, HID_);
  transp_bf16<<<dim3(16, 32), 256, 0, stream>>>(wkv, wkvT, HID_, 1024);
  transp_bf16<<<dim3(32, 32), 256, 0, stream>>>(wo, woT, HID_, HID_);
  gemm_bt<u16><<<dim3(32, 16), 256, 0, stream>>>(xbf, wqT, XQ, M, HID_, HID_);
  gemm_bt<u16><<<dim3(32, 8), 256, 0, stream>>>(cbf, wkvT, CKV, M, 1024, HID_);
  knorm_deint<<<dim3(32, 4, 2), 256, 0, stream>>>(CKV, nkw, Kb, Vt);
  attn<<<dim3(16, 16, 2), 256, 0, stream>>>(XQ, nqw, Kb, Vt, AO);
  gemm_bt<float><<<dim3(32, 16), 256, 0, stream>>>(AO, woT, out, M, HID_, HID_);
}